// Round 1
// baseline (48.324 us; speedup 1.0000x reference)
//
#include <hip/hip_runtime.h>
#include <math.h>

// Problem: x[32,3,512,512] f32; dark-channel = min over (c, 20x20 window with
// replicate pad, pl=9 pr=10); output scalar |1 - mean(dark)|.
//
// Fused single-pass tiled kernel:
//   - channel-min with clamped (== replicate-pad) indexing into LDS (83x83)
//   - horizontal sliding-min (window 20) into LDS (83x64)
//   - vertical sliding-min (window 20) + local accumulation
//   - block partial sums -> d_ws; tiny second kernel reduces deterministically.

#define BATCH 32
#define HH 512
#define WW 512
#define KWIN 20
#define PLPAD 9          // left/top pad; right/bottom is 10
#define TH 64            // output tile rows per block
#define TW 64            // output tile cols per block
#define IH (TH + KWIN - 1)   // 83 input rows needed
#define IW (TW + KWIN - 1)   // 83 input cols needed
#define CMS 84               // padded row stride (multiple of 4 for float4 LDS reads)

__device__ __forceinline__ float fmin3(float a, float b, float c) {
    return fminf(fminf(a, b), c);
}

__launch_bounds__(256)
__global__ void dark_tile_kernel(const float* __restrict__ x,
                                 float* __restrict__ partials)
{
    __shared__ float cm[IH * CMS];   // 83*84*4 = 27888 B, channel-min tile
    __shared__ float hm[IH * TW];    // 83*64*4 = 21248 B, horizontal-min tile
    __shared__ float red[4];

    const int b  = blockIdx.z;
    const int h0 = blockIdx.y * TH;
    const int w0 = blockIdx.x * TW;
    const int t  = threadIdx.x;

    const float* xb = x + (size_t)b * 3 * HH * WW;

    // ---- Step 1: channel-min into cm, replicate pad via index clamp ----
    for (int idx = t; idx < IH * IW; idx += 256) {
        int r = idx / IW;
        int c = idx - r * IW;
        int gr = h0 - PLPAD + r; gr = gr < 0 ? 0 : (gr > HH - 1 ? HH - 1 : gr);
        int gc = w0 - PLPAD + c; gc = gc < 0 ? 0 : (gc > WW - 1 ? WW - 1 : gc);
        int off = gr * WW + gc;
        float a0 = xb[off];
        float a1 = xb[off + HH * WW];
        float a2 = xb[off + 2 * HH * WW];
        cm[r * CMS + c] = fmin3(a0, a1, a2);
    }
    __syncthreads();

    // ---- Step 2: horizontal sliding min (window 20), 4 outputs per task ----
    // tasks: 83 rows x 16 quads (j0 = 4*q), reads v[0..22] as 6 float4
    for (int task = t; task < IH * 16; task += 256) {
        int r  = task >> 4;
        int q  = task & 15;
        int j0 = q << 2;
        const float4* p = (const float4*)&cm[r * CMS + j0];
        float4 f0 = p[0], f1 = p[1], f2 = p[2], f3 = p[3], f4 = p[4], f5 = p[5];
        float v0 = f0.x, v1 = f0.y, v2 = f0.z, v3 = f0.w;
        float v4 = f1.x, v5 = f1.y, v6 = f1.z, v7 = f1.w;
        float v8 = f2.x, v9 = f2.y, v10 = f2.z, v11 = f2.w;
        float v12 = f3.x, v13 = f3.y, v14 = f3.z, v15 = f3.w;
        float v16 = f4.x, v17 = f4.y, v18 = f4.z, v19 = f4.w;
        float v20 = f5.x, v21 = f5.y, v22 = f5.z;
        // shared interior: M = min(v3..v19)
        float M = v3;
        M = fminf(M, v4);  M = fminf(M, v5);  M = fminf(M, v6);  M = fminf(M, v7);
        M = fminf(M, v8);  M = fminf(M, v9);  M = fminf(M, v10); M = fminf(M, v11);
        M = fminf(M, v12); M = fminf(M, v13); M = fminf(M, v14); M = fminf(M, v15);
        M = fminf(M, v16); M = fminf(M, v17); M = fminf(M, v18); M = fminf(M, v19);
        float o0 = fminf(fmin3(v0, v1, v2), M);
        float o1 = fminf(fminf(v1, v2), fminf(M, v20));
        float o2 = fminf(fminf(v2, M), fminf(v20, v21));
        float o3 = fminf(fminf(M, v20), fminf(v21, v22));
        *(float4*)&hm[r * TW + j0] = make_float4(o0, o1, o2, o3);
    }
    __syncthreads();

    // ---- Step 3: vertical sliding min (window 20) + accumulate ----
    // 1024 tasks: j = task&63, i0 = 4*(task>>6); each produces 4 outputs
    float sum = 0.f;
    for (int task = t; task < TW * 16; task += 256) {
        int j  = task & 63;
        int i0 = (task >> 6) << 2;
        float v[23];
        #pragma unroll
        for (int d = 0; d < 23; ++d) v[d] = hm[(i0 + d) * TW + j];
        float M = v[3];
        #pragma unroll
        for (int d = 4; d <= 19; ++d) M = fminf(M, v[d]);
        float o0 = fminf(fmin3(v[0], v[1], v[2]), M);
        float o1 = fminf(fminf(v[1], v[2]), fminf(M, v[20]));
        float o2 = fminf(fminf(v[2], M), fminf(v[20], v[21]));
        float o3 = fminf(fminf(M, v[20]), fminf(v[21], v[22]));
        sum += o0 + o1 + o2 + o3;
    }

    // ---- Block reduction (deterministic) ----
    #pragma unroll
    for (int off = 32; off; off >>= 1) sum += __shfl_down(sum, off);
    if ((t & 63) == 0) red[t >> 6] = sum;
    __syncthreads();
    if (t == 0) {
        float ps = red[0] + red[1] + red[2] + red[3];
        int blockId = (blockIdx.z * gridDim.y + blockIdx.y) * gridDim.x + blockIdx.x;
        partials[blockId] = ps;
    }
}

__launch_bounds__(256)
__global__ void dark_reduce_kernel(const float* __restrict__ partials, int n,
                                   float* __restrict__ out)
{
    __shared__ float red[4];
    int t = threadIdx.x;
    float s = 0.f;
    for (int i = t; i < n; i += 256) s += partials[i];
    #pragma unroll
    for (int off = 32; off; off >>= 1) s += __shfl_down(s, off);
    if ((t & 63) == 0) red[t >> 6] = s;
    __syncthreads();
    if (t == 0) {
        float total = red[0] + red[1] + red[2] + red[3];
        float mean = total / (float)((long long)BATCH * HH * WW);
        out[0] = fabsf(1.0f - mean);
    }
}

extern "C" void kernel_launch(void* const* d_in, const int* in_sizes, int n_in,
                              void* d_out, int out_size, void* d_ws, size_t ws_size,
                              hipStream_t stream) {
    const float* x = (const float*)d_in[0];
    float* out = (float*)d_out;
    float* partials = (float*)d_ws;   // 2048 floats = 8 KB

    dim3 grid(WW / TW, HH / TH, BATCH);   // 8 x 8 x 32 = 2048 blocks
    dark_tile_kernel<<<grid, 256, 0, stream>>>(x, partials);
    dark_reduce_kernel<<<1, 256, 0, stream>>>(partials, (WW / TW) * (HH / TH) * BATCH, out);
}